// Round 6
// baseline (617.571 us; speedup 1.0000x reference)
//
#include <hip/hip_runtime.h>
#include <math.h>

#define L_SEQ 1024
#define DM 128
#define JC 32
#define NCH 16   // chunks per j-half (512/32)

// workspace layout (floats)
#define OFF_KHAT 0                         // [L][4][48]
#define OFF_QHAT (L_SEQ * 192)             // [L][4][48]
#define OFF_V    (OFF_QHAT + L_SEQ * 192)  // [L][128]
#define OFF_VG   (OFF_V + L_SEQ * DM)      // [L][48]

typedef __attribute__((address_space(1))) const void* gas_t;
typedef __attribute__((address_space(3))) void* las_t;

__device__ __forceinline__ void async16(const float4* g, float4* l) {
    __builtin_amdgcn_global_load_lds((gas_t)g, (las_t)l, 16, 0, 0);
}
// raw barrier: drain LDS ops only; async global->LDS stays in flight
#define ASYNC_BAR() asm volatile("s_waitcnt lgkmcnt(0)\n\ts_barrier" ::: "memory")
#define VM_DRAIN()  asm volatile("s_waitcnt vmcnt(0)" ::: "memory")

// ---------------- kernel 1: LN + projections + rotations + staging (1 row/block, grid=1024) ----------------
__global__ __launch_bounds__(256) void ipa_prep(
    const float* __restrict__ single, const float* __restrict__ T,
    const float* __restrict__ w_C, const float* __restrict__ ln_g, const float* __restrict__ ln_b,
    const float* __restrict__ Wq, const float* __restrict__ Wk, const float* __restrict__ Wv,
    const float* __restrict__ Wqpt, const float* __restrict__ Wkpt, const float* __restrict__ Wvpt,
    float* __restrict__ ws)
{
    __shared__ float z_lds[128];
    __shared__ float proj[528];
    __shared__ float qg[4][4][3];
    __shared__ float kg[4][4][3];
    __shared__ float cq[4], ck[4];

    const int t = threadIdx.x;
    const int i = blockIdx.x;

    if (t < 64) {
        float x0 = single[i*DM + t];
        float x1 = single[i*DM + 64 + t];
        float s = x0 + x1, s2 = x0*x0 + x1*x1;
        #pragma unroll
        for (int off = 1; off < 64; off <<= 1) { s += __shfl_xor(s, off); s2 += __shfl_xor(s2, off); }
        float mu = s * 0.0078125f;
        float var = s2 * 0.0078125f - mu*mu;
        float rs = rsqrtf(var + 1e-5f);
        z_lds[t]      = (x0 - mu) * rs * ln_g[t]      + ln_b[t];
        z_lds[t + 64] = (x1 - mu) * rs * ln_g[t + 64] + ln_b[t + 64];
    }
    __syncthreads();

    for (int cc = t; cc < 528; cc += 256) {
        const float* W; int col, ncol;
        if (cc < 128)      { W = Wq;   col = cc;       ncol = 128; }
        else if (cc < 256) { W = Wk;   col = cc - 128; ncol = 128; }
        else if (cc < 384) { W = Wv;   col = cc - 256; ncol = 128; }
        else if (cc < 432) { W = Wqpt; col = cc - 384; ncol = 48;  }
        else if (cc < 480) { W = Wkpt; col = cc - 432; ncol = 48;  }
        else               { W = Wvpt; col = cc - 480; ncol = 48;  }
        float a = 0.f;
        #pragma unroll 8
        for (int k = 0; k < 128; ++k)
            a = fmaf(z_lds[k], W[k*ncol + col], a);
        proj[cc] = a;
    }
    __syncthreads();

    if (t < 16) {
        int h = t >> 2, p = t & 3;
        float R[3][3], tt[3];
        #pragma unroll
        for (int x = 0; x < 3; ++x) {
            #pragma unroll
            for (int y = 0; y < 3; ++y) R[x][y] = T[i*16 + x*4 + y];
            tt[x] = T[i*16 + x*4 + 3];
        }
        int base = 384 + (h*4 + p)*3;
        float q0 = proj[base],    q1 = proj[base+1],  q2 = proj[base+2];
        float k0 = proj[base+48], k1 = proj[base+49], k2 = proj[base+50];
        float v0 = proj[base+96], v1 = proj[base+97], v2 = proj[base+98];
        #pragma unroll
        for (int x = 0; x < 3; ++x) {
            float qq = R[x][0]*q0 + R[x][1]*q1 + R[x][2]*q2 + tt[x];
            float kk = R[x][0]*k0 + R[x][1]*k1 + R[x][2]*k2 + tt[x];
            float vv = R[x][0]*v0 + R[x][1]*v1 + R[x][2]*v2 + tt[x];
            qg[h][p][x] = qq;
            kg[h][p][x] = kk;
            ws[OFF_VG + (size_t)i*48 + h*12 + p*3 + x] = vv;
        }
    }
    __syncthreads();

    if (t < 8) {
        int h = t >> 1, isk = t & 1;
        float w = w_C[h];
        float wp = log1pf(__expf(w));
        float sq = 0.f;
        #pragma unroll
        for (int p = 0; p < 4; ++p)
            #pragma unroll
            for (int x = 0; x < 3; ++x) {
                float g = isk ? kg[h][p][x] : qg[h][p][x];
                sq += g*g;
            }
        float c = -0.5f * wp * sq;
        if (isk) ck[h] = c; else cq[h] = c;
    }
    __syncthreads();

    if (t < 128) ws[OFF_V + (size_t)i*DM + t] = proj[256 + t];
    const float scale_attn = 0.17677669529663687f;  // 32^-0.5
    if (t < 192) {
        int h = t / 48, k = t % 48;
        float w = w_C[h];
        float wp = log1pf(__expf(w));
        float kv, qv;
        if (k < 32) {
            kv = proj[128 + h*32 + k];
            qv = scale_attn * proj[h*32 + k];
        } else if (k < 44) {
            int e = k - 32;
            kv = kg[h][e/3][e%3];
            qv = wp * qg[h][e/3][e%3];
        } else if (k == 44) { kv = ck[h]; qv = 1.0f; }
        else if (k == 45)   { kv = 1.0f; qv = cq[h]; }
        else                { kv = 0.f;  qv = 0.f; }
        ws[OFF_KHAT + (size_t)i*192 + t] = kv;
        ws[OFF_QHAT + (size_t)i*192 + t] = qv;
    }
}

// ---------------- kernel 2: 512-thread block, 2 rows, split-j across two 4-wave groups ----------------
// Group g = wave>>2 owns j in [g*512, g*512+512), head = wave&3. Per-group pair dbuf, 16 chunks,
// 2 barriers/chunk. End: flash merge of the two j-halves in LDS. 16 waves/CU (2 blocks x 8 waves).
__global__ __launch_bounds__(512, 4) void ipa_attn(
    const float* __restrict__ single, const float* __restrict__ pair,
    const float* __restrict__ T, const float* __restrict__ Wb,
    const float* __restrict__ Wout, const float* __restrict__ b_out,
    const float* __restrict__ ws, float* __restrict__ out)
{
    // LDS: 65536 + 1664 + 1088 + 2048 + 64 = 70400 B -> 2 blocks/CU
    __shared__ __align__(16) float4 pair_w[2][2][2][32][16]; // [g][buf][row][j][slot], slot = c4 ^ (j&7)
    __shared__ __align__(16) float4 qhat_lds[2][4][13];      // [row][h][k4] pad 13
    __shared__ __align__(16) float  wbt_lds[4][68];          // Wb^T [h][c] pad 68
    __shared__ __align__(16) float  p_lds[2][4][2][32];      // [g][h][row][j]
    __shared__ float alpha_lds[2][4][2];                     // [g][h][row]

    const int t = threadIdx.x;
    const int w = t >> 6, lane = t & 63;
    const int g = w >> 2, hw = w & 3;
    const int gt = t & 255;                 // thread index within group
    const int i0 = blockIdx.x * 2;

    // lane roles
    const int j_s = lane & 31, kc = lane >> 5;       // phase S: j x {k/c}-half
    const int d4  = lane & 7,  jg_s = lane >> 3;     // o_s
    const int c4p = lane >> 4, jg_p = lane & 15;     // o_pair
    const int g4  = lane & 3,  jg_g = lane >> 2;     // o_pt_g
    const int g4c = (g4 < 3) ? g4 : 0;

    float4* pwf = &pair_w[0][0][0][0][0];
    float4* gp  = pwf + g*2048;             // group's 32 KB region (2 bufs x 1024 float4)
    const float4* pair4 = (const float4*)pair;
    const float4* kh4   = (const float4*)(ws + OFF_KHAT);
    const float4* qh4   = (const float4*)(ws + OFF_QHAT);
    const float4* v4    = (const float4*)(ws + OFF_V);
    const float4* vg4   = (const float4*)(ws + OFF_VG);
    const float4* wbt4  = (const float4*)&wbt_lds[0][0];   // [h][17]

    // prologue: stage chunk 0 -> buf 0 (4 async16/thread; LDS lane-linear per wave)
    #pragma unroll
    for (int it = 0; it < 4; ++it) {
        int idx = it*256 + gt;
        int row = idx >> 9, j = (idx >> 4) & 31, slot = idx & 15;
        int c4 = slot ^ (j & 7);
        async16(pair4 + ((size_t)(i0+row)*L_SEQ + g*512 + j)*16 + c4, gp + idx);
    }
    if (t < 96) {
        int r = t / 48, rest = t % 48;
        qhat_lds[r][rest/12][rest%12] = qh4[(size_t)(i0+r)*48 + rest];
    } else if (t < 160) {
        int c = t - 96;
        float4 w4 = ((const float4*)Wb)[c];
        wbt_lds[0][c] = w4.x; wbt_lds[1][c] = w4.y; wbt_lds[2][c] = w4.z; wbt_lds[3][c] = w4.w;
    }
    __syncthreads();   // publishes qhat/wbt; also drains prologue stage (vmcnt at barrier)

    float m0r = -INFINITY, m1r = -INFINITY, l0r = 0.f, l1r = 0.f;
    float4 accp[2][4], accs[2], accg[2];
    #pragma unroll
    for (int r = 0; r < 2; ++r) {
        accs[r] = make_float4(0.f,0.f,0.f,0.f);
        accg[r] = make_float4(0.f,0.f,0.f,0.f);
        #pragma unroll
        for (int h = 0; h < 4; ++h) accp[r][h] = make_float4(0.f,0.f,0.f,0.f);
    }

    for (int ch = 0; ch < NCH; ++ch) {
        const int cur = ch & 1;
        const int j0 = g*512 + ch*JC;

        VM_DRAIN();     // own chunk-ch stage ops retired (issued last iter)
        ASYNC_BAR();    // all waves: chunk ch visible; phase A of ch-1 done

        // kh loads (head hw, row j0+j_s, k-half kc)
        float4 kh[6];
        {
            const float4* kp = kh4 + (size_t)(j0 + j_s)*48 + hw*12 + kc*6;
            #pragma unroll
            for (int k4 = 0; k4 < 6; ++k4) kh[k4] = kp[k4];
        }

        // ---- phase S (fused bias): lane = (j_s, kc), both rows ----
        const float4* prow0 = gp + cur*1024 +       j_s*16;
        const float4* prow1 = gp + cur*1024 + 512 + j_s*16;
        const float4* wrow  = wbt4 + hw*17;
        float b0 = 0.f, b1 = 0.f;
        #pragma unroll
        for (int cq = 0; cq < 8; ++cq) {
            int c4 = kc*8 + cq;
            int sw = c4 ^ (j_s & 7);
            float4 wh  = wrow[c4];
            float4 pv0 = prow0[sw];
            float4 pv1 = prow1[sw];
            b0 += pv0.x*wh.x + pv0.y*wh.y + pv0.z*wh.z + pv0.w*wh.w;
            b1 += pv1.x*wh.x + pv1.y*wh.y + pv1.z*wh.z + pv1.w*wh.w;
        }
        float d0a=0.f, d0b=0.f, d1a=0.f, d1b=0.f;
        #pragma unroll
        for (int k4 = 0; k4 < 6; k4 += 2) {
            float4 q0a = qhat_lds[0][hw][kc*6+k4], q0b = qhat_lds[0][hw][kc*6+k4+1];
            float4 q1a = qhat_lds[1][hw][kc*6+k4], q1b = qhat_lds[1][hw][kc*6+k4+1];
            float4 ka = kh[k4], kb = kh[k4+1];
            d0a = fmaf(ka.x, q0a.x, d0a); d0a = fmaf(ka.y, q0a.y, d0a);
            d0a = fmaf(ka.z, q0a.z, d0a); d0a = fmaf(ka.w, q0a.w, d0a);
            d0b = fmaf(kb.x, q0b.x, d0b); d0b = fmaf(kb.y, q0b.y, d0b);
            d0b = fmaf(kb.z, q0b.z, d0b); d0b = fmaf(kb.w, q0b.w, d0b);
            d1a = fmaf(ka.x, q1a.x, d1a); d1a = fmaf(ka.y, q1a.y, d1a);
            d1a = fmaf(ka.z, q1a.z, d1a); d1a = fmaf(ka.w, q1a.w, d1a);
            d1b = fmaf(kb.x, q1b.x, d1b); d1b = fmaf(kb.y, q1b.y, d1b);
            d1b = fmaf(kb.z, q1b.z, d1b); d1b = fmaf(kb.w, q1b.w, d1b);
        }
        float part0 = d0a + d0b + b0;
        float part1 = d1a + d1b + b1;
        float logit0 = part0 + __shfl_xor(part0, 32);   // combine k/c halves
        float logit1 = part1 + __shfl_xor(part1, 32);

        // online softmax, two independent row chains
        float c0 = logit0, c1 = logit1;
        #pragma unroll
        for (int off = 1; off < 32; off <<= 1) {
            c0 = fmaxf(c0, __shfl_xor(c0, off));
            c1 = fmaxf(c1, __shfl_xor(c1, off));
        }
        float mn0 = fmaxf(m0r, c0), mn1 = fmaxf(m1r, c1);
        float al0 = __expf(m0r - mn0), al1 = __expf(m1r - mn1);
        float p0 = __expf(logit0 - mn0), p1 = __expf(logit1 - mn1);
        l0r = l0r*al0 + p0;  l1r = l1r*al1 + p1;
        m0r = mn0;  m1r = mn1;
        if (kc == 0) { p_lds[g][hw][0][j_s] = p0; p_lds[g][hw][1][j_s] = p1; }
        if (lane == 0) { alpha_lds[g][hw][0] = al0; alpha_lds[g][hw][1] = al1; }

        // phase-A global inputs (V shared across rows)
        float4 vv[4];
        #pragma unroll
        for (int jj = 0; jj < 4; ++jj)
            vv[jj] = v4[(size_t)(j0 + jg_s + 8*jj)*32 + hw*8 + d4];
        float4 gvv[2];
        #pragma unroll
        for (int jj = 0; jj < 2; ++jj)
            gvv[jj] = vg4[(size_t)(j0 + jg_g + 16*jj)*12 + hw*3 + g4c];

        // stage chunk ch+1 -> buf[1-cur] (safe: phase S/A read buf[cur]; ch-1 readers past top barrier)
        if (ch + 1 < NCH) {
            #pragma unroll
            for (int it = 0; it < 4; ++it) {
                int idx = it*256 + gt;
                int row = idx >> 9, j = (idx >> 4) & 31, slot = idx & 15;
                int c4 = slot ^ (j & 7);
                async16(pair4 + ((size_t)(i0+row)*L_SEQ + g*512 + (ch+1)*JC + j)*16 + c4,
                        gp + (1-cur)*1024 + idx);
            }
        }
        ASYNC_BAR();    // p_lds/alpha visible (async stage stays in flight)

        // ---- phase A: rescale + accumulate ----
        {
            float al[4][2];
            #pragma unroll
            for (int h = 0; h < 4; ++h) { al[h][0] = alpha_lds[g][h][0]; al[h][1] = alpha_lds[g][h][1]; }
            #pragma unroll
            for (int r = 0; r < 2; ++r)
                #pragma unroll
                for (int h = 0; h < 4; ++h) {
                    float a = al[h][r];
                    accp[r][h].x *= a; accp[r][h].y *= a; accp[r][h].z *= a; accp[r][h].w *= a;
                }
            accs[0].x *= al0; accs[0].y *= al0; accs[0].z *= al0; accs[0].w *= al0;
            accs[1].x *= al1; accs[1].y *= al1; accs[1].z *= al1; accs[1].w *= al1;
            accg[0].x *= al0; accg[0].y *= al0; accg[0].z *= al0; accg[0].w *= al0;
            accg[1].x *= al1; accg[1].y *= al1; accg[1].z *= al1; accg[1].w *= al1;

            // o_pair: c4 = hw*4 + c4p, j = jg_p + 16*jj, both rows
            #pragma unroll
            for (int jj = 0; jj < 2; ++jj) {
                int j = jg_p + 16*jj;
                int sw = (hw*4 + c4p) ^ (j & 7);
                float4 pv0 = gp[cur*1024 +       j*16 + sw];
                float4 pv1 = gp[cur*1024 + 512 + j*16 + sw];
                float p00 = p_lds[g][0][0][j], p01 = p_lds[g][1][0][j];
                float p02 = p_lds[g][2][0][j], p03 = p_lds[g][3][0][j];
                float p10 = p_lds[g][0][1][j], p11 = p_lds[g][1][1][j];
                float p12 = p_lds[g][2][1][j], p13 = p_lds[g][3][1][j];
                accp[0][0].x = fmaf(p00, pv0.x, accp[0][0].x); accp[0][0].y = fmaf(p00, pv0.y, accp[0][0].y);
                accp[0][0].z = fmaf(p00, pv0.z, accp[0][0].z); accp[0][0].w = fmaf(p00, pv0.w, accp[0][0].w);
                accp[0][1].x = fmaf(p01, pv0.x, accp[0][1].x); accp[0][1].y = fmaf(p01, pv0.y, accp[0][1].y);
                accp[0][1].z = fmaf(p01, pv0.z, accp[0][1].z); accp[0][1].w = fmaf(p01, pv0.w, accp[0][1].w);
                accp[0][2].x = fmaf(p02, pv0.x, accp[0][2].x); accp[0][2].y = fmaf(p02, pv0.y, accp[0][2].y);
                accp[0][2].z = fmaf(p02, pv0.z, accp[0][2].z); accp[0][2].w = fmaf(p02, pv0.w, accp[0][2].w);
                accp[0][3].x = fmaf(p03, pv0.x, accp[0][3].x); accp[0][3].y = fmaf(p03, pv0.y, accp[0][3].y);
                accp[0][3].z = fmaf(p03, pv0.z, accp[0][3].z); accp[0][3].w = fmaf(p03, pv0.w, accp[0][3].w);
                accp[1][0].x = fmaf(p10, pv1.x, accp[1][0].x); accp[1][0].y = fmaf(p10, pv1.y, accp[1][0].y);
                accp[1][0].z = fmaf(p10, pv1.z, accp[1][0].z); accp[1][0].w = fmaf(p10, pv1.w, accp[1][0].w);
                accp[1][1].x = fmaf(p11, pv1.x, accp[1][1].x); accp[1][1].y = fmaf(p11, pv1.y, accp[1][1].y);
                accp[1][1].z = fmaf(p11, pv1.z, accp[1][1].z); accp[1][1].w = fmaf(p11, pv1.w, accp[1][1].w);
                accp[1][2].x = fmaf(p12, pv1.x, accp[1][2].x); accp[1][2].y = fmaf(p12, pv1.y, accp[1][2].y);
                accp[1][2].z = fmaf(p12, pv1.z, accp[1][2].z); accp[1][2].w = fmaf(p12, pv1.w, accp[1][2].w);
                accp[1][3].x = fmaf(p13, pv1.x, accp[1][3].x); accp[1][3].y = fmaf(p13, pv1.y, accp[1][3].y);
                accp[1][3].z = fmaf(p13, pv1.z, accp[1][3].z); accp[1][3].w = fmaf(p13, pv1.w, accp[1][3].w);
            }
            // o_s: head hw
            #pragma unroll
            for (int jj = 0; jj < 4; ++jj) {
                int j = jg_s + 8*jj;
                float pa0 = p_lds[g][hw][0][j], pa1 = p_lds[g][hw][1][j];
                accs[0].x = fmaf(pa0, vv[jj].x, accs[0].x); accs[0].y = fmaf(pa0, vv[jj].y, accs[0].y);
                accs[0].z = fmaf(pa0, vv[jj].z, accs[0].z); accs[0].w = fmaf(pa0, vv[jj].w, accs[0].w);
                accs[1].x = fmaf(pa1, vv[jj].x, accs[1].x); accs[1].y = fmaf(pa1, vv[jj].y, accs[1].y);
                accs[1].z = fmaf(pa1, vv[jj].z, accs[1].z); accs[1].w = fmaf(pa1, vv[jj].w, accs[1].w);
            }
            // o_pt_g: head hw
            #pragma unroll
            for (int jj = 0; jj < 2; ++jj) {
                int j = jg_g + 16*jj;
                float pg0 = p_lds[g][hw][0][j], pg1 = p_lds[g][hw][1][j];
                accg[0].x = fmaf(pg0, gvv[jj].x, accg[0].x); accg[0].y = fmaf(pg0, gvv[jj].y, accg[0].y);
                accg[0].z = fmaf(pg0, gvv[jj].z, accg[0].z); accg[0].w = fmaf(pg0, gvv[jj].w, accg[0].w);
                accg[1].x = fmaf(pg1, gvv[jj].x, accg[1].x); accg[1].y = fmaf(pg1, gvv[jj].y, accg[1].y);
                accg[1].z = fmaf(pg1, gvv[jj].z, accg[1].z); accg[1].w = fmaf(pg1, gvv[jj].w, accg[1].w);
            }
        }
    }

    // ---- intra-wave reductions ----
    #pragma unroll
    for (int off = 1; off < 32; off <<= 1) { l0r += __shfl_xor(l0r, off); l1r += __shfl_xor(l1r, off); }
    #pragma unroll
    for (int r = 0; r < 2; ++r) {
        #pragma unroll
        for (int h = 0; h < 4; ++h)
            #pragma unroll
            for (int off = 1; off < 16; off <<= 1) {
                accp[r][h].x += __shfl_xor(accp[r][h].x, off);
                accp[r][h].y += __shfl_xor(accp[r][h].y, off);
                accp[r][h].z += __shfl_xor(accp[r][h].z, off);
                accp[r][h].w += __shfl_xor(accp[r][h].w, off);
            }
        #pragma unroll
        for (int off = 8; off < 64; off <<= 1) {
            accs[r].x += __shfl_xor(accs[r].x, off); accs[r].y += __shfl_xor(accs[r].y, off);
            accs[r].z += __shfl_xor(accs[r].z, off); accs[r].w += __shfl_xor(accs[r].w, off);
        }
        #pragma unroll
        for (int off = 4; off < 64; off <<= 1) {
            accg[r].x += __shfl_xor(accg[r].x, off); accg[r].y += __shfl_xor(accg[r].y, off);
            accg[r].z += __shfl_xor(accg[r].z, off); accg[r].w += __shfl_xor(accg[r].w, off);
        }
    }

    // ---- publish per-group partials (g0 -> buf0 of g0 [0,1024); g1 -> buf0 of g1 [8192,9216)) ----
    // layout per group: r*512 + {0..255 o_pair, 256..383 o_s, 384..431 og, 432..435 l, 436..439 m}
    float* scratch = (float*)pwf;
    float* cw = scratch + g*8192;
    #pragma unroll
    for (int r = 0; r < 2; ++r) {
        if ((lane & 15) == 0) {
            #pragma unroll
            for (int h = 0; h < 4; ++h)
                *(float4*)&cw[r*512 + h*64 + (hw*4 + (lane>>4))*4] = accp[r][h];
        }
        if (lane < 8) *(float4*)&cw[r*512 + 256 + hw*32 + lane*4] = accs[r];
        if (lane < 3) *(float4*)&cw[r*512 + 384 + hw*12 + lane*4] = accg[r];
    }
    if (lane == 0) {
        cw[0*512 + 432 + hw] = l0r; cw[0*512 + 436 + hw] = m0r;
        cw[1*512 + 432 + hw] = l1r; cw[1*512 + 436 + hw] = m1r;
    }
    __syncthreads();

    // merge scratch at floats [2048, 4096) (g0 buf0 upper half — untouched by publishes)
    float* u   = scratch + 2048;          // [2][448]
    float* og2 = scratch + 2048 + 896;    // [2][48]
    float* wts = scratch + 2048 + 992;    // [2][8]: [r][g*4+h]
    float* ivs = scratch + 2048 + 1008;   // [2][4]
    float* tmp = scratch + 2048 + 1024;   // [2][128]

    if (t < 8) {
        int r = t >> 2, h = t & 3;
        float mA = scratch[r*512 + 436 + h], mB = scratch[8192 + r*512 + 436 + h];
        float M = fmaxf(mA, mB);
        float wA = __expf(mA - M), wB = __expf(mB - M);
        float L = scratch[r*512 + 432 + h]*wA + scratch[8192 + r*512 + 432 + h]*wB;
        wts[r*8 + h] = wA; wts[r*8 + 4 + h] = wB;
        ivs[r*4 + h] = 1.f / L;
    }
    __syncthreads();

    {   // o_pair merge: 512 threads -> (r, 256 cols)
        int r = t >> 8, q = t & 255, hp = q >> 6;
        float v = scratch[r*512 + q]*wts[r*8 + hp] + scratch[8192 + r*512 + q]*wts[r*8 + 4 + hp];
        u[r*448 + 128 + q] = v * ivs[r*4 + hp];
    }
    if (t < 256) {  // o_s merge
        int r = t >> 7, q = t & 127, hs = q >> 5;
        float v = scratch[r*512 + 256 + q]*wts[r*8 + hs] + scratch[8192 + r*512 + 256 + q]*wts[r*8 + 4 + hs];
        u[r*448 + q] = v * ivs[r*4 + hs];
    }
    if (t < 96) {   // o_pt_g merge
        int r = t / 48, qg = t % 48, hg = qg / 12;
        float v = scratch[r*512 + 384 + qg]*wts[r*8 + hg] + scratch[8192 + r*512 + 384 + qg]*wts[r*8 + 4 + hg];
        og2[r*48 + qg] = v * ivs[r*4 + hg];
    }
    __syncthreads();

    if (t < 32) {   // inverse rigid transform + norm
        int r = t >> 4, idx = t & 15, h = idx >> 2, p = idx & 3;
        int ii = i0 + r;
        float R[3][3], tt[3];
        #pragma unroll
        for (int x = 0; x < 3; ++x) {
            #pragma unroll
            for (int y = 0; y < 3; ++y) R[x][y] = T[ii*16 + x*4 + y];
            tt[x] = T[ii*16 + x*4 + 3];
        }
        float v0 = og2[r*48 + h*12 + p*3+0] - tt[0];
        float v1 = og2[r*48 + h*12 + p*3+1] - tt[1];
        float v2 = og2[r*48 + h*12 + p*3+2] - tt[2];
        float n2 = 0.f;
        #pragma unroll
        for (int x = 0; x < 3; ++x) {
            float o = R[0][x]*v0 + R[1][x]*v1 + R[2][x]*v2;
            u[r*448 + 384 + h*12 + p*3 + x] = o;
            n2 += o*o;
        }
        u[r*448 + 432 + h*4 + p] = sqrtf(n2);
    }
    __syncthreads();

    // final matmul: (kq, r, d) over 512 threads, split-k halves
    {
        int r = (t >> 7) & 1, d = t & 127, kq = t >> 8;
        int ii = i0 + r;
        float acc = 0.f;
        const float4* u4 = (const float4*)(u + r*448);
        #pragma unroll 4
        for (int k4 = kq*56; k4 < kq*56 + 56; ++k4) {
            float4 uu = u4[k4];
            const float* wp = Wout + (size_t)(k4*4)*128 + d;
            acc = fmaf(uu.x, wp[0],   acc);
            acc = fmaf(uu.y, wp[128], acc);
            acc = fmaf(uu.z, wp[256], acc);
            acc = fmaf(uu.w, wp[384], acc);
        }
        if (kq) tmp[r*128 + d] = acc;
        __syncthreads();
        if (!kq) out[(size_t)ii*DM + d] = single[(size_t)ii*DM + d] + b_out[d] + acc + tmp[r*128 + d];
    }
}

extern "C" void kernel_launch(void* const* d_in, const int* in_sizes, int n_in,
                              void* d_out, int out_size, void* d_ws, size_t ws_size,
                              hipStream_t stream)
{
    const float* single = (const float*)d_in[0];
    const float* pair   = (const float*)d_in[1];
    const float* T      = (const float*)d_in[2];
    const float* w_C    = (const float*)d_in[3];
    const float* ln_g   = (const float*)d_in[4];
    const float* ln_b   = (const float*)d_in[5];
    const float* Wq     = (const float*)d_in[6];
    const float* Wk     = (const float*)d_in[7];
    const float* Wv     = (const float*)d_in[8];
    const float* Wqpt   = (const float*)d_in[9];
    const float* Wkpt   = (const float*)d_in[10];
    const float* Wvpt   = (const float*)d_in[11];
    const float* Wb     = (const float*)d_in[12];
    const float* Wout   = (const float*)d_in[13];
    const float* b_out  = (const float*)d_in[14];
    float* out = (float*)d_out;
    float* ws  = (float*)d_ws;

    ipa_prep<<<1024, 256, 0, stream>>>(single, T, w_C, ln_g, ln_b, Wq, Wk, Wv, Wqpt, Wkpt, Wvpt, ws);
    ipa_attn<<<512, 512, 0, stream>>>(single, pair, T, Wb, Wout, b_out, ws, out);
}

// Round 7
// 469.682 us; speedup vs baseline: 1.3149x; 1.3149x over previous
//
#include <hip/hip_runtime.h>
#include <math.h>

#define L_SEQ 1024
#define DM 128
#define JC 32
#define NCH 16   // chunks per j-half (512/32)

// workspace layout (floats)
#define OFF_KHAT 0                         // [L][4][48]
#define OFF_QHAT (L_SEQ * 192)             // [L][4][48]
#define OFF_V    (OFF_QHAT + L_SEQ * 192)  // [L][128]
#define OFF_VG   (OFF_V + L_SEQ * DM)      // [L][48]
#define OFF_PART (OFF_VG + L_SEQ * 48)     // [L][2][448] flash partials per (row, j-half)

typedef __attribute__((address_space(1))) const void* gas_t;
typedef __attribute__((address_space(3))) void* las_t;

__device__ __forceinline__ void async16(const float4* g, float4* l) {
    __builtin_amdgcn_global_load_lds((gas_t)g, (las_t)l, 16, 0, 0);
}
// raw barrier: drain LDS ops only; async global->LDS stays in flight
#define ASYNC_BAR() asm volatile("s_waitcnt lgkmcnt(0)\n\ts_barrier" ::: "memory")
#define VM_DRAIN()  asm volatile("s_waitcnt vmcnt(0)" ::: "memory")

// ---------------- kernel 1: LN + projections + rotations + staging (1 row/block, grid=1024) ----------------
__global__ __launch_bounds__(256) void ipa_prep(
    const float* __restrict__ single, const float* __restrict__ T,
    const float* __restrict__ w_C, const float* __restrict__ ln_g, const float* __restrict__ ln_b,
    const float* __restrict__ Wq, const float* __restrict__ Wk, const float* __restrict__ Wv,
    const float* __restrict__ Wqpt, const float* __restrict__ Wkpt, const float* __restrict__ Wvpt,
    float* __restrict__ ws)
{
    __shared__ float z_lds[128];
    __shared__ float proj[528];
    __shared__ float qg[4][4][3];
    __shared__ float kg[4][4][3];
    __shared__ float cq[4], ck[4];

    const int t = threadIdx.x;
    const int i = blockIdx.x;

    if (t < 64) {
        float x0 = single[i*DM + t];
        float x1 = single[i*DM + 64 + t];
        float s = x0 + x1, s2 = x0*x0 + x1*x1;
        #pragma unroll
        for (int off = 1; off < 64; off <<= 1) { s += __shfl_xor(s, off); s2 += __shfl_xor(s2, off); }
        float mu = s * 0.0078125f;
        float var = s2 * 0.0078125f - mu*mu;
        float rs = rsqrtf(var + 1e-5f);
        z_lds[t]      = (x0 - mu) * rs * ln_g[t]      + ln_b[t];
        z_lds[t + 64] = (x1 - mu) * rs * ln_g[t + 64] + ln_b[t + 64];
    }
    __syncthreads();

    for (int cc = t; cc < 528; cc += 256) {
        const float* W; int col, ncol;
        if (cc < 128)      { W = Wq;   col = cc;       ncol = 128; }
        else if (cc < 256) { W = Wk;   col = cc - 128; ncol = 128; }
        else if (cc < 384) { W = Wv;   col = cc - 256; ncol = 128; }
        else if (cc < 432) { W = Wqpt; col = cc - 384; ncol = 48;  }
        else if (cc < 480) { W = Wkpt; col = cc - 432; ncol = 48;  }
        else               { W = Wvpt; col = cc - 480; ncol = 48;  }
        float a = 0.f;
        #pragma unroll 8
        for (int k = 0; k < 128; ++k)
            a = fmaf(z_lds[k], W[k*ncol + col], a);
        proj[cc] = a;
    }
    __syncthreads();

    if (t < 16) {
        int h = t >> 2, p = t & 3;
        float R[3][3], tt[3];
        #pragma unroll
        for (int x = 0; x < 3; ++x) {
            #pragma unroll
            for (int y = 0; y < 3; ++y) R[x][y] = T[i*16 + x*4 + y];
            tt[x] = T[i*16 + x*4 + 3];
        }
        int base = 384 + (h*4 + p)*3;
        float q0 = proj[base],    q1 = proj[base+1],  q2 = proj[base+2];
        float k0 = proj[base+48], k1 = proj[base+49], k2 = proj[base+50];
        float v0 = proj[base+96], v1 = proj[base+97], v2 = proj[base+98];
        #pragma unroll
        for (int x = 0; x < 3; ++x) {
            float qq = R[x][0]*q0 + R[x][1]*q1 + R[x][2]*q2 + tt[x];
            float kk = R[x][0]*k0 + R[x][1]*k1 + R[x][2]*k2 + tt[x];
            float vv = R[x][0]*v0 + R[x][1]*v1 + R[x][2]*v2 + tt[x];
            qg[h][p][x] = qq;
            kg[h][p][x] = kk;
            ws[OFF_VG + (size_t)i*48 + h*12 + p*3 + x] = vv;
        }
    }
    __syncthreads();

    if (t < 8) {
        int h = t >> 1, isk = t & 1;
        float w = w_C[h];
        float wp = log1pf(__expf(w));
        float sq = 0.f;
        #pragma unroll
        for (int p = 0; p < 4; ++p)
            #pragma unroll
            for (int x = 0; x < 3; ++x) {
                float g = isk ? kg[h][p][x] : qg[h][p][x];
                sq += g*g;
            }
        float c = -0.5f * wp * sq;
        if (isk) ck[h] = c; else cq[h] = c;
    }
    __syncthreads();

    if (t < 128) ws[OFF_V + (size_t)i*DM + t] = proj[256 + t];
    const float scale_attn = 0.17677669529663687f;  // 32^-0.5
    if (t < 192) {
        int h = t / 48, k = t % 48;
        float w = w_C[h];
        float wp = log1pf(__expf(w));
        float kv, qv;
        if (k < 32) {
            kv = proj[128 + h*32 + k];
            qv = scale_attn * proj[h*32 + k];
        } else if (k < 44) {
            int e = k - 32;
            kv = kg[h][e/3][e%3];
            qv = wp * qg[h][e/3][e%3];
        } else if (k == 44) { kv = ck[h]; qv = 1.0f; }
        else if (k == 45)   { kv = 1.0f; qv = cq[h]; }
        else                { kv = 0.f;  qv = 0.f; }
        ws[OFF_KHAT + (size_t)i*192 + t] = kv;
        ws[OFF_QHAT + (size_t)i*192 + t] = qv;
    }
}

// ---------------- kernel 2: split-j flash IPA. Block = (row-pair, j-half). grid=1024, 4 blocks/CU -----------
// R0's 2-row 4-wave phase pipeline, 16 chunks, 2 barriers/chunk (bias fused via kc lane-split).
// Writes unnormalized partials (acc, l, m) to ws; ipa_combine merges halves.
__global__ __launch_bounds__(256, 2) void ipa_attn(
    const float* __restrict__ pair, const float* __restrict__ Wb,
    float* __restrict__ ws)
{
    // LDS: 32768 + 1664 + 1088 + 1024 + 32 = 36576 B -> 4 blocks/CU
    __shared__ __align__(16) float4 pair_lds[2][2][32][16]; // [buf][row][j][slot], slot = c4 ^ (j&7)
    __shared__ __align__(16) float4 qhat_lds[2][4][13];     // [row][h][k4] pad 13
    __shared__ __align__(16) float  wbt_lds[4][68];         // Wb^T [h][c] pad 68 (row stride 272B = 17 float4)
    __shared__ __align__(16) float  p_lds[4][2][32];        // [h][row][j]
    __shared__ float alpha_lds[4][2];                       // [h][row]

    const int t = threadIdx.x;
    const int hw = t >> 6, lane = t & 63;      // wave = head
    const int i0 = (blockIdx.x >> 1) * 2;
    const int g  = blockIdx.x & 1;             // j-half: [g*512, g*512+512)

    // lane roles
    const int j_s = lane & 31, kc = lane >> 5;       // phase S: j x {k/c}-half
    const int d4  = lane & 7,  jg_s = lane >> 3;     // o_s
    const int c4p = lane >> 4, jg_p = lane & 15;     // o_pair
    const int g4  = lane & 3,  jg_g = lane >> 2;     // o_pt_g
    const int g4c = (g4 < 3) ? g4 : 0;

    const float4* pair4 = (const float4*)pair;
    const float4* kh4   = (const float4*)(ws + OFF_KHAT);
    const float4* qh4   = (const float4*)(ws + OFF_QHAT);
    const float4* v4    = (const float4*)(ws + OFF_V);
    const float4* vg4   = (const float4*)(ws + OFF_VG);
    float4* plds = &pair_lds[0][0][0][0];
    const float4* wbt4 = (const float4*)&wbt_lds[0][0];    // row stride 17 float4

    // prologue: stage chunk 0 -> buf 0 (4 async16/thread; LDS lane-linear, global swizzle-permuted)
    #pragma unroll
    for (int it = 0; it < 4; ++it) {
        int idx = it*256 + t;
        int row = idx >> 9, j = (idx >> 4) & 31, slot = idx & 15;
        int c4 = slot ^ (j & 7);
        async16(pair4 + ((size_t)(i0+row)*L_SEQ + g*512 + j)*16 + c4, plds + idx);
    }
    if (t < 96) {
        int r = t / 48, rest = t % 48;
        qhat_lds[r][rest/12][rest%12] = qh4[(size_t)(i0+r)*48 + rest];
    } else if (t < 160) {
        int c = t - 96;
        float4 w4 = ((const float4*)Wb)[c];
        wbt_lds[0][c] = w4.x; wbt_lds[1][c] = w4.y; wbt_lds[2][c] = w4.z; wbt_lds[3][c] = w4.w;
    }
    __syncthreads();   // publishes qhat/wbt; compiler drains vmcnt here (prologue only)

    float m0r = -INFINITY, m1r = -INFINITY, l0r = 0.f, l1r = 0.f;
    float4 accp[2][4], accs[2], accg[2];
    #pragma unroll
    for (int r = 0; r < 2; ++r) {
        accs[r] = make_float4(0.f,0.f,0.f,0.f);
        accg[r] = make_float4(0.f,0.f,0.f,0.f);
        #pragma unroll
        for (int h = 0; h < 4; ++h) accp[r][h] = make_float4(0.f,0.f,0.f,0.f);
    }

    for (int ch = 0; ch < NCH; ++ch) {
        const int cur = ch & 1;
        const int j0 = g*512 + ch*JC;

        VM_DRAIN();     // chunk ch's stage (issued last iter) retired for this wave
        ASYNC_BAR();    // all waves: chunk ch visible; chunk ch-1 readers done

        // stage chunk ch+1 -> buf[1-cur] (free: ch-1 readers are past the barrier)
        if (ch + 1 < NCH) {
            #pragma unroll
            for (int it = 0; it < 4; ++it) {
                int idx = it*256 + t;
                int row = idx >> 9, j = (idx >> 4) & 31, slot = idx & 15;
                int c4 = slot ^ (j & 7);
                async16(pair4 + ((size_t)(i0+row)*L_SEQ + g*512 + (ch+1)*JC + j)*16 + c4,
                        plds + (1-cur)*1024 + idx);
            }
        }

        // kh loads (j-dependent only; head hw, k-half kc)
        float4 kh[6];
        {
            const float4* kp = kh4 + (size_t)(j0 + j_s)*48 + hw*12 + kc*6;
            #pragma unroll
            for (int k4 = 0; k4 < 6; ++k4) kh[k4] = kp[k4];
        }

        // ---- phase S (fused bias): lane = (j_s, kc); both rows ----
        const float4* prow0 = plds + cur*1024 +       j_s*16;
        const float4* prow1 = plds + cur*1024 + 512 + j_s*16;
        const float4* wrow  = wbt4 + hw*17;
        float b0 = 0.f, b1 = 0.f;
        #pragma unroll
        for (int cq = 0; cq < 8; ++cq) {
            int c4 = kc*8 + cq;
            int sw = c4 ^ (j_s & 7);
            float4 wh  = wrow[c4];
            float4 pv0 = prow0[sw];
            float4 pv1 = prow1[sw];
            b0 += pv0.x*wh.x + pv0.y*wh.y + pv0.z*wh.z + pv0.w*wh.w;
            b1 += pv1.x*wh.x + pv1.y*wh.y + pv1.z*wh.z + pv1.w*wh.w;
        }
        float d0a=0.f, d0b=0.f, d1a=0.f, d1b=0.f;
        #pragma unroll
        for (int k4 = 0; k4 < 6; k4 += 2) {
            float4 q0a = qhat_lds[0][hw][kc*6+k4], q0b = qhat_lds[0][hw][kc*6+k4+1];
            float4 q1a = qhat_lds[1][hw][kc*6+k4], q1b = qhat_lds[1][hw][kc*6+k4+1];
            float4 ka = kh[k4], kb = kh[k4+1];
            d0a = fmaf(ka.x, q0a.x, d0a); d0a = fmaf(ka.y, q0a.y, d0a);
            d0a = fmaf(ka.z, q0a.z, d0a); d0a = fmaf(ka.w, q0a.w, d0a);
            d0b = fmaf(kb.x, q0b.x, d0b); d0b = fmaf(kb.y, q0b.y, d0b);
            d0b = fmaf(kb.z, q0b.z, d0b); d0b = fmaf(kb.w, q0b.w, d0b);
            d1a = fmaf(ka.x, q1a.x, d1a); d1a = fmaf(ka.y, q1a.y, d1a);
            d1a = fmaf(ka.z, q1a.z, d1a); d1a = fmaf(ka.w, q1a.w, d1a);
            d1b = fmaf(kb.x, q1b.x, d1b); d1b = fmaf(kb.y, q1b.y, d1b);
            d1b = fmaf(kb.z, q1b.z, d1b); d1b = fmaf(kb.w, q1b.w, d1b);
        }
        float part0 = d0a + d0b + b0;
        float part1 = d1a + d1b + b1;
        float logit0 = part0 + __shfl_xor(part0, 32);   // combine k/c halves (both halves get full logit)
        float logit1 = part1 + __shfl_xor(part1, 32);

        // online softmax, two independent row chains (reduce over 32 j's within each half)
        float c0 = logit0, c1 = logit1;
        #pragma unroll
        for (int off = 1; off < 32; off <<= 1) {
            c0 = fmaxf(c0, __shfl_xor(c0, off));
            c1 = fmaxf(c1, __shfl_xor(c1, off));
        }
        float mn0 = fmaxf(m0r, c0), mn1 = fmaxf(m1r, c1);
        float al0 = __expf(m0r - mn0), al1 = __expf(m1r - mn1);
        float p0 = __expf(logit0 - mn0), p1 = __expf(logit1 - mn1);
        l0r = l0r*al0 + p0;  l1r = l1r*al1 + p1;
        m0r = mn0;  m1r = mn1;
        if (kc == 0) { p_lds[hw][0][j_s] = p0; p_lds[hw][1][j_s] = p1; }
        if (lane == 0) { alpha_lds[hw][0] = al0; alpha_lds[hw][1] = al1; }

        // phase-A global inputs (V/VG shared across rows)
        float4 vv[4];
        #pragma unroll
        for (int jj = 0; jj < 4; ++jj)
            vv[jj] = v4[(size_t)(j0 + jg_s + 8*jj)*32 + hw*8 + d4];
        float4 gvv[2];
        #pragma unroll
        for (int jj = 0; jj < 2; ++jj)
            gvv[jj] = vg4[(size_t)(j0 + jg_g + 16*jj)*12 + hw*3 + g4c];

        ASYNC_BAR();    // p_lds/alpha visible (async stage stays in flight)

        // ---- phase A: rescale + accumulate ----
        {
            float al[4][2];
            #pragma unroll
            for (int h = 0; h < 4; ++h) { al[h][0] = alpha_lds[h][0]; al[h][1] = alpha_lds[h][1]; }
            #pragma unroll
            for (int r = 0; r < 2; ++r)
                #pragma unroll
                for (int h = 0; h < 4; ++h) {
                    float a = al[h][r];
                    accp[r][h].x *= a; accp[r][h].y *= a; accp[r][h].z *= a; accp[r][h].w *= a;
                }
            accs[0].x *= al0; accs[0].y *= al0; accs[0].z *= al0; accs[0].w *= al0;
            accs[1].x *= al1; accs[1].y *= al1; accs[1].z *= al1; accs[1].w *= al1;
            accg[0].x *= al0; accg[0].y *= al0; accg[0].z *= al0; accg[0].w *= al0;
            accg[1].x *= al1; accg[1].y *= al1; accg[1].z *= al1; accg[1].w *= al1;

            // o_pair: c4 = hw*4 + c4p, j = jg_p + 16*jj, both rows
            #pragma unroll
            for (int jj = 0; jj < 2; ++jj) {
                int j = jg_p + 16*jj;
                int sw = (hw*4 + c4p) ^ (j & 7);
                float4 pv0 = plds[cur*1024 +       j*16 + sw];
                float4 pv1 = plds[cur*1024 + 512 + j*16 + sw];
                float p00 = p_lds[0][0][j], p01 = p_lds[1][0][j];
                float p02 = p_lds[2][0][j], p03 = p_lds[3][0][j];
                float p10 = p_lds[0][1][j], p11 = p_lds[1][1][j];
                float p12 = p_lds[2][1][j], p13 = p_lds[3][1][j];
                accp[0][0].x = fmaf(p00, pv0.x, accp[0][0].x); accp[0][0].y = fmaf(p00, pv0.y, accp[0][0].y);
                accp[0][0].z = fmaf(p00, pv0.z, accp[0][0].z); accp[0][0].w = fmaf(p00, pv0.w, accp[0][0].w);
                accp[0][1].x = fmaf(p01, pv0.x, accp[0][1].x); accp[0][1].y = fmaf(p01, pv0.y, accp[0][1].y);
                accp[0][1].z = fmaf(p01, pv0.z, accp[0][1].z); accp[0][1].w = fmaf(p01, pv0.w, accp[0][1].w);
                accp[0][2].x = fmaf(p02, pv0.x, accp[0][2].x); accp[0][2].y = fmaf(p02, pv0.y, accp[0][2].y);
                accp[0][2].z = fmaf(p02, pv0.z, accp[0][2].z); accp[0][2].w = fmaf(p02, pv0.w, accp[0][2].w);
                accp[0][3].x = fmaf(p03, pv0.x, accp[0][3].x); accp[0][3].y = fmaf(p03, pv0.y, accp[0][3].y);
                accp[0][3].z = fmaf(p03, pv0.z, accp[0][3].z); accp[0][3].w = fmaf(p03, pv0.w, accp[0][3].w);
                accp[1][0].x = fmaf(p10, pv1.x, accp[1][0].x); accp[1][0].y = fmaf(p10, pv1.y, accp[1][0].y);
                accp[1][0].z = fmaf(p10, pv1.z, accp[1][0].z); accp[1][0].w = fmaf(p10, pv1.w, accp[1][0].w);
                accp[1][1].x = fmaf(p11, pv1.x, accp[1][1].x); accp[1][1].y = fmaf(p11, pv1.y, accp[1][1].y);
                accp[1][1].z = fmaf(p11, pv1.z, accp[1][1].z); accp[1][1].w = fmaf(p11, pv1.w, accp[1][1].w);
                accp[1][2].x = fmaf(p12, pv1.x, accp[1][2].x); accp[1][2].y = fmaf(p12, pv1.y, accp[1][2].y);
                accp[1][2].z = fmaf(p12, pv1.z, accp[1][2].z); accp[1][2].w = fmaf(p12, pv1.w, accp[1][2].w);
                accp[1][3].x = fmaf(p13, pv1.x, accp[1][3].x); accp[1][3].y = fmaf(p13, pv1.y, accp[1][3].y);
                accp[1][3].z = fmaf(p13, pv1.z, accp[1][3].z); accp[1][3].w = fmaf(p13, pv1.w, accp[1][3].w);
            }
            // o_s: head hw
            #pragma unroll
            for (int jj = 0; jj < 4; ++jj) {
                int j = jg_s + 8*jj;
                float pa0 = p_lds[hw][0][j], pa1 = p_lds[hw][1][j];
                accs[0].x = fmaf(pa0, vv[jj].x, accs[0].x); accs[0].y = fmaf(pa0, vv[jj].y, accs[0].y);
                accs[0].z = fmaf(pa0, vv[jj].z, accs[0].z); accs[0].w = fmaf(pa0, vv[jj].w, accs[0].w);
                accs[1].x = fmaf(pa1, vv[jj].x, accs[1].x); accs[1].y = fmaf(pa1, vv[jj].y, accs[1].y);
                accs[1].z = fmaf(pa1, vv[jj].z, accs[1].z); accs[1].w = fmaf(pa1, vv[jj].w, accs[1].w);
            }
            // o_pt_g: head hw
            #pragma unroll
            for (int jj = 0; jj < 2; ++jj) {
                int j = jg_g + 16*jj;
                float pg0 = p_lds[hw][0][j], pg1 = p_lds[hw][1][j];
                accg[0].x = fmaf(pg0, gvv[jj].x, accg[0].x); accg[0].y = fmaf(pg0, gvv[jj].y, accg[0].y);
                accg[0].z = fmaf(pg0, gvv[jj].z, accg[0].z); accg[0].w = fmaf(pg0, gvv[jj].w, accg[0].w);
                accg[1].x = fmaf(pg1, gvv[jj].x, accg[1].x); accg[1].y = fmaf(pg1, gvv[jj].y, accg[1].y);
                accg[1].z = fmaf(pg1, gvv[jj].z, accg[1].z); accg[1].w = fmaf(pg1, gvv[jj].w, accg[1].w);
            }
        }
    }

    // ---- intra-wave reductions ----
    #pragma unroll
    for (int off = 1; off < 32; off <<= 1) { l0r += __shfl_xor(l0r, off); l1r += __shfl_xor(l1r, off); }
    #pragma unroll
    for (int r = 0; r < 2; ++r) {
        #pragma unroll
        for (int h = 0; h < 4; ++h)
            #pragma unroll
            for (int off = 1; off < 16; off <<= 1) {
                accp[r][h].x += __shfl_xor(accp[r][h].x, off);
                accp[r][h].y += __shfl_xor(accp[r][h].y, off);
                accp[r][h].z += __shfl_xor(accp[r][h].z, off);
                accp[r][h].w += __shfl_xor(accp[r][h].w, off);
            }
        #pragma unroll
        for (int off = 8; off < 64; off <<= 1) {
            accs[r].x += __shfl_xor(accs[r].x, off); accs[r].y += __shfl_xor(accs[r].y, off);
            accs[r].z += __shfl_xor(accs[r].z, off); accs[r].w += __shfl_xor(accs[r].w, off);
        }
        #pragma unroll
        for (int off = 4; off < 64; off <<= 1) {
            accg[r].x += __shfl_xor(accg[r].x, off); accg[r].y += __shfl_xor(accg[r].y, off);
            accg[r].z += __shfl_xor(accg[r].z, off); accg[r].w += __shfl_xor(accg[r].w, off);
        }
    }

    // ---- write unnormalized partials to ws: [row][half][448] ----
    float* pb0 = ws + OFF_PART + ((size_t)(i0+0)*2 + g)*448;
    float* pb1 = ws + OFF_PART + ((size_t)(i0+1)*2 + g)*448;
    if ((lane & 15) == 0) {
        int c4 = hw*4 + (lane >> 4);
        #pragma unroll
        for (int h = 0; h < 4; ++h) {
            *(float4*)&pb0[h*64 + c4*4] = accp[0][h];
            *(float4*)&pb1[h*64 + c4*4] = accp[1][h];
        }
    }
    if (lane < 8) {
        *(float4*)&pb0[256 + hw*32 + lane*4] = accs[0];
        *(float4*)&pb1[256 + hw*32 + lane*4] = accs[1];
    }
    if (lane < 3) {
        *(float4*)&pb0[384 + hw*12 + lane*4] = accg[0];
        *(float4*)&pb1[384 + hw*12 + lane*4] = accg[1];
    }
    if (lane == 0) {
        pb0[432 + hw] = l0r; pb0[436 + hw] = m0r;
        pb1[432 + hw] = l1r; pb1[436 + hw] = m1r;
    }
}

// ---------------- kernel 3: merge j-halves + rigid transform + output matmul (2 rows/block, grid=512) -------
__global__ __launch_bounds__(256) void ipa_combine(
    const float* __restrict__ single, const float* __restrict__ T,
    const float* __restrict__ Wout, const float* __restrict__ b_out,
    const float* __restrict__ ws, float* __restrict__ out)
{
    __shared__ __align__(16) float u[2][448];
    __shared__ float og2[2][48];
    __shared__ float wts[2][8];    // [r][g*4+h]
    __shared__ float ivs[2][4];

    const int t = threadIdx.x;
    const int i0 = blockIdx.x * 2;
    const float* P = ws + OFF_PART;

    if (t < 8) {
        int r = t >> 2, h = t & 3;
        const float* pA = P + ((size_t)(i0+r)*2 + 0)*448;
        const float* pB = P + ((size_t)(i0+r)*2 + 1)*448;
        float mA = pA[436 + h], mB = pB[436 + h];
        float M = fmaxf(mA, mB);
        float wA = __expf(mA - M), wB = __expf(mB - M);
        float L = pA[432 + h]*wA + pB[432 + h]*wB;
        wts[r][h] = wA; wts[r][4 + h] = wB;
        ivs[r][h] = 1.f / L;
    }
    __syncthreads();

    #pragma unroll
    for (int r = 0; r < 2; ++r) {
        const float* pA = P + ((size_t)(i0+r)*2 + 0)*448;
        const float* pB = P + ((size_t)(i0+r)*2 + 1)*448;
        {   // o_pair: 256 elems (h*64+c)
            int q = t, hp = q >> 6;
            u[r][128 + q] = (pA[q]*wts[r][hp] + pB[q]*wts[r][4 + hp]) * ivs[r][hp];
        }
        if (t < 128) {   // o_s (h*32+d)
            int hs = t >> 5;
            u[r][t] = (pA[256 + t]*wts[r][hs] + pB[256 + t]*wts[r][4 + hs]) * ivs[r][hs];
        }
        if (t < 48) {    // o_pt_g (h*12+pe)
            int hg = t / 12;
            og2[r][t] = (pA[384 + t]*wts[r][hg] + pB[384 + t]*wts[r][4 + hg]) * ivs[r][hg];
        }
    }
    __syncthreads();

    if (t < 32) {   // inverse rigid transform + norms
        int r = t >> 4, idx = t & 15, h = idx >> 2, p = idx & 3;
        int ii = i0 + r;
        float R[3][3], tt[3];
        #pragma unroll
        for (int x = 0; x < 3; ++x) {
            #pragma unroll
            for (int y = 0; y < 3; ++y) R[x][y] = T[ii*16 + x*4 + y];
            tt[x] = T[ii*16 + x*4 + 3];
        }
        float v0 = og2[r][h*12 + p*3+0] - tt[0];
        float v1 = og2[r][h*12 + p*3+1] - tt[1];
        float v2 = og2[r][h*12 + p*3+2] - tt[2];
        float n2 = 0.f;
        #pragma unroll
        for (int x = 0; x < 3; ++x) {
            float o = R[0][x]*v0 + R[1][x]*v1 + R[2][x]*v2;
            u[r][384 + h*12 + p*3 + x] = o;
            n2 += o*o;
        }
        u[r][432 + h*4 + p] = sqrtf(n2);
    }
    __syncthreads();

    // final matmul: thread -> (row, d), full 448-dot
    {
        int r = t >> 7, d = t & 127;
        int ii = i0 + r;
        float acc = single[ii*DM + d] + b_out[d];
        const float4* u4 = (const float4*)u[r];
        #pragma unroll 4
        for (int k4 = 0; k4 < 112; ++k4) {
            float4 uu = u4[k4];
            const float* wp = Wout + (size_t)(k4*4)*128 + d;
            acc = fmaf(uu.x, wp[0],   acc);
            acc = fmaf(uu.y, wp[128], acc);
            acc = fmaf(uu.z, wp[256], acc);
            acc = fmaf(uu.w, wp[384], acc);
        }
        out[(size_t)ii*DM + d] = acc;
    }
}

extern "C" void kernel_launch(void* const* d_in, const int* in_sizes, int n_in,
                              void* d_out, int out_size, void* d_ws, size_t ws_size,
                              hipStream_t stream)
{
    const float* single = (const float*)d_in[0];
    const float* pair   = (const float*)d_in[1];
    const float* T      = (const float*)d_in[2];
    const float* w_C    = (const float*)d_in[3];
    const float* ln_g   = (const float*)d_in[4];
    const float* ln_b   = (const float*)d_in[5];
    const float* Wq     = (const float*)d_in[6];
    const float* Wk     = (const float*)d_in[7];
    const float* Wv     = (const float*)d_in[8];
    const float* Wqpt   = (const float*)d_in[9];
    const float* Wkpt   = (const float*)d_in[10];
    const float* Wvpt   = (const float*)d_in[11];
    const float* Wb     = (const float*)d_in[12];
    const float* Wout   = (const float*)d_in[13];
    const float* b_out  = (const float*)d_in[14];
    float* out = (float*)d_out;
    float* ws  = (float*)d_ws;

    ipa_prep<<<1024, 256, 0, stream>>>(single, T, w_C, ln_g, ln_b, Wq, Wk, Wv, Wqpt, Wkpt, Wvpt, ws);
    ipa_attn<<<1024, 256, 0, stream>>>(pair, Wb, ws);
    ipa_combine<<<512, 256, 0, stream>>>(single, T, Wout, b_out, ws, out);
}